// Round 2
// baseline (3644.894 us; speedup 1.0000x reference)
//
#include <hip/hip_runtime.h>
#include <hip/hip_bf16.h>
#include <cstdint>
#include <cstddef>

// Problem dims
#define B_    256
#define T_    64
#define H_    512
#define DIN_  2048
#define BT_   (B_ * T_)     // 16384
#define NPRE_ 4864          // precompute columns (see layout below)
#define NSPLIT_ 2688        // cols < NSPLIT_ come from input_feats; rest from aux0
#define NCAT_ 1536          // per-step gh columns: h_r|h_i|h_n

// Cpre column layout (all bf16):
//   X-group (from input_feats):
#define C_IN    0           // i_n                     [512]
#define C_VIR   512         // Wv o Wih_r              [512]
#define C_VII   1024        // Wv o Wih_i              [512]
#define C_ZIR   1536        // Wqk^T o Wih_r           [512]
#define C_ZII   2048        // Wqk^T o Wih_i           [512]
#define C_CR1   2560        // scalar bqk . i_r        [1]  (cols 2562..2687 pad)
#define C_CI1   2561        // scalar bqk . i_i        [1]
//   A-group (from aux0):
#define C_VT1   2688        // Wv o W_fh0_1            [512]
#define C_VT2   3200        // Wv o W_fh0_2            [512]
#define C_ZT1   3712        // Wqk^T o W_fh0_1         [512]
#define C_ZT2   4224        // Wqk^T o W_fh0_2         [512]
#define C_CR0   4736        // scalar bqk . t1         [1]  (cols 4738..4863 pad)
#define C_CI0   4737        // scalar bqk . t2         [1]

typedef __attribute__((ext_vector_type(8))) __bf16 bf16x8;
typedef __attribute__((ext_vector_type(4))) float  f32x4;

__device__ __forceinline__ float bf2f(unsigned short u) {
    union { unsigned int i; float f; } v; v.i = ((unsigned int)u) << 16; return v.f;
}
__device__ __forceinline__ unsigned short f2bf(float f) {
    union { float f; unsigned int i; } v; v.f = f;
    unsigned int x = v.i;
    return (unsigned short)((x + 0x7fffu + ((x >> 16) & 1u)) >> 16);
}

// async global->LDS, 16B per lane; lds base must be wave-uniform, HW adds lane*16
__device__ __forceinline__ void gl_lds16(const void* g, void* lbase, int lane) {
#if __has_builtin(__builtin_amdgcn_global_load_lds)
    __builtin_amdgcn_global_load_lds(
        (const __attribute__((address_space(1))) unsigned int*)(unsigned long long)g,
        (__attribute__((address_space(3))) unsigned int*)(unsigned int)(unsigned long long)lbase,
        16, 0, 0);
#else
    ((uint4*)lbase)[lane] = *(const uint4*)g;   // slow fallback, same semantics
#endif
}

// ---------------- cast fp32 -> bf16, 4 elems/thread ----------------
__global__ void cast4_kernel(const float* __restrict__ src,
                             unsigned short* __restrict__ dst, int n4) {
    int i = blockIdx.x * blockDim.x + threadIdx.x;
    if (i >= n4) return;
    const float4 v = ((const float4*)src)[i];
    ushort4 o;
    o.x = f2bf(v.x); o.y = f2bf(v.y); o.z = f2bf(v.z); o.w = f2bf(v.w);
    ((ushort4*)dst)[i] = o;
}

// ---------------- transpose + cast: dst[c,r] = src[r,c], bf16 out ----------------
__global__ __launch_bounds__(256)
void tcast_kernel(const float* __restrict__ src, unsigned short* __restrict__ dst,
                  int R, int C) {
    __shared__ float s[32][33];
    const int tx = threadIdx.x, ty = threadIdx.y; // 32 x 8
    const int r0 = blockIdx.y * 32, c0 = blockIdx.x * 32;
    #pragma unroll
    for (int i = 0; i < 4; i++)
        s[ty + i * 8][tx] = src[(size_t)(r0 + ty + i * 8) * C + c0 + tx];
    __syncthreads();
    #pragma unroll
    for (int i = 0; i < 4; i++)
        dst[(size_t)(c0 + ty + i * 8) * R + r0 + tx] = f2bf(s[tx][ty + i * 8]);
}

// Q[h,j] = sum_o arg0[o,h]*arg1[o,j]  (called with (Wq, Wk) -> Q = Wq^T Wk), bf16 out
__global__ __launch_bounds__(256)
void wqk_kernel(const float* __restrict__ Wa, const float* __restrict__ Wb,
                unsigned short* __restrict__ Wout) {
    __shared__ float sk[16][17], sq[16][17];
    const int tid = threadIdx.x;
    const int tx = tid & 15, ty = tid >> 4;
    const int a0 = blockIdx.y * 16, b0 = blockIdx.x * 16;
    float acc = 0.f;
    for (int o0 = 0; o0 < 512; o0 += 16) {
        sk[ty][tx] = Wa[(o0 + ty) * 512 + a0 + tx];
        sq[ty][tx] = Wb[(o0 + ty) * 512 + b0 + tx];
        __syncthreads();
        #pragma unroll
        for (int oo = 0; oo < 16; oo++)
            acc = fmaf(sk[oo][ty], sq[oo][tx], acc);
        __syncthreads();
    }
    Wout[(size_t)(a0 + ty) * 512 + b0 + tx] = f2bf(acc);
}

// out[i] = sum_j M[i*ld+j] * v[j]
__global__ void rowdot_kernel(const float* __restrict__ M, int ld, int k,
                              const float* __restrict__ v, float* __restrict__ out, int n) {
    int i = blockIdx.x * blockDim.x + threadIdx.x;
    if (i >= n) return;
    float a = 0.f;
    for (int j = 0; j < k; j++) a = fmaf(M[(size_t)i * ld + j], v[j], a);
    out[i] = a;
}

// out[h] = sum_o M[o*ld+h] * v[o]
__global__ void coldot_f32_kernel(const float* __restrict__ M, int ld, int rows,
                                  const float* __restrict__ v, float* __restrict__ out, int n) {
    int h = blockIdx.x * blockDim.x + threadIdx.x;
    if (h >= n) return;
    float a = 0.f;
    for (int o = 0; o < rows; o++) a = fmaf(M[(size_t)o * ld + h], v[o], a);
    out[h] = a;
}
__global__ void coldot_bf16_kernel(const float* __restrict__ M, int ld, int rows,
                                   const float* __restrict__ v,
                                   unsigned short* __restrict__ out, int n) {
    int h = blockIdx.x * blockDim.x + threadIdx.x;
    if (h >= n) return;
    float a = 0.f;
    for (int o = 0; o < rows; o++) a = fmaf(M[(size_t)o * ld + h], v[o], a);
    out[h] = f2bf(a);
}
// out[0] = a . b
__global__ void dot_kernel(const float* __restrict__ a, const float* __restrict__ b,
                           int n, float* __restrict__ out) {
    __shared__ float red[8];
    int tid = threadIdx.x; // 512
    float s = 0.f;
    for (int i = tid; i < n; i += 512) s = fmaf(a[i], b[i], s);
    #pragma unroll
    for (int off = 32; off > 0; off >>= 1) s += __shfl_down(s, off);
    if ((tid & 63) == 0) red[tid >> 6] = s;
    __syncthreads();
    if (tid == 0) { float t = 0.f; for (int w = 0; w < 8; w++) t += red[w]; out[0] = t; }
}

// ---------------- LDS-staged bf16 GEMM (m97 pattern) ----------------
// C[m,n] = sum_k A[m,k]*W[n,k] (+bias[n]).  A = (n0<nsplit)?A0:A1, lda==K.
// W row-major [N x ldw].  128x128 tile, BK=64, global_load_lds 16B staging with
// XOR chunk swizzle (2-way LDS bank aliasing = free on gfx950).
// mode 0: fp32 out to Cout.  mode 1: bf16 out to Cout.
// mode 2: bf16 dual-dest: m<msplit -> Cout, else Cout2 (no bias).
__global__ __launch_bounds__(256)
void gemm_lds(const unsigned short* __restrict__ A0,
              const unsigned short* __restrict__ A1, int nsplit,
              const unsigned short* __restrict__ W, int ldw,
              const float* __restrict__ bias,
              void* __restrict__ Cout, void* __restrict__ Cout2,
              int mode, int msplit, int N, int K, int ldc) {
    __shared__ __align__(16) unsigned short sA[128 * 64];
    __shared__ __align__(16) unsigned short sB[128 * 64];
    const int n0 = blockIdx.x * 128;
    const int m0 = blockIdx.y * 128;
    const unsigned short* A = (n0 < nsplit) ? A0 : A1;
    const int tid = threadIdx.x;
    const int w = tid >> 6, lane = tid & 63;
    const int wm = (w >> 1) * 64, wn = (w & 1) * 64;

    // staging: lane -> (row srow, chunk schunk) of a 8-row x 8-chunk slab
    const int srow = lane >> 3;                       // 0..7
    const int schunk = (lane & 7) ^ (srow & 7);       // XOR swizzle
    const unsigned short* ag = A + (size_t)(m0 + w * 8 + srow) * K + schunk * 8;
    const unsigned short* bg = W + (size_t)(n0 + w * 8 + srow) * ldw + schunk * 8;

    const int fr = lane & 15;   // frag row (A) / col (B)
    const int fc = lane >> 4;   // 0..3: k-chunk select

    f32x4 acc[4][4];
    #pragma unroll
    for (int i = 0; i < 4; i++)
        #pragma unroll
        for (int j = 0; j < 4; j++) {
            acc[i][j].x = 0.f; acc[i][j].y = 0.f; acc[i][j].z = 0.f; acc[i][j].w = 0.f;
        }

    for (int k0 = 0; k0 < K; k0 += 64) {
        #pragma unroll
        for (int i = 0; i < 4; i++) {
            gl_lds16(ag + (size_t)i * 32 * K + k0, &sA[(i * 32 + w * 8) * 64], lane);
            gl_lds16(bg + (size_t)i * 32 * ldw + k0, &sB[(i * 32 + w * 8) * 64], lane);
        }
        __syncthreads();
        #pragma unroll
        for (int kk = 0; kk < 2; kk++) {
            const int c = kk * 4 + fc;
            bf16x8 a[4], b[4];
            #pragma unroll
            for (int i = 0; i < 4; i++) {
                const int r = wm + i * 16 + fr;
                a[i] = *(const bf16x8*)&sA[r * 64 + ((c ^ (r & 7)) * 8)];
            }
            #pragma unroll
            for (int j = 0; j < 4; j++) {
                const int r = wn + j * 16 + fr;
                b[j] = *(const bf16x8*)&sB[r * 64 + ((c ^ (r & 7)) * 8)];
            }
            #pragma unroll
            for (int i = 0; i < 4; i++)
                #pragma unroll
                for (int j = 0; j < 4; j++)
                    acc[i][j] = __builtin_amdgcn_mfma_f32_16x16x32_bf16(a[i], b[j], acc[i][j], 0, 0, 0);
        }
        __syncthreads();
    }

    // epilogue: C/D layout col=lane&15, row=(lane>>4)*4+reg
    #pragma unroll
    for (int i = 0; i < 4; i++) {
        #pragma unroll
        for (int j = 0; j < 4; j++) {
            const int n = n0 + wn + j * 16 + fr;
            const float bb = bias ? bias[n] : 0.f;
            #pragma unroll
            for (int r = 0; r < 4; r++) {
                const int m = m0 + wm + i * 16 + fc * 4 + r;
                const float vv = acc[i][j][r] + bb;
                if (mode == 0) {
                    ((float*)Cout)[(size_t)m * ldc + n] = vv;
                } else if (mode == 1) {
                    ((unsigned short*)Cout)[(size_t)m * ldc + n] = f2bf(vv);
                } else {
                    if (m < msplit)
                        ((unsigned short*)Cout)[(size_t)m * ldc + n] = f2bf(vv);
                    else
                        ((unsigned short*)Cout2)[(size_t)(m - msplit) * ldc + n] = f2bf(vv);
                }
            }
        }
    }
}

// ---------------- per-step: scores (4 dots) + probs + ctx blend + gates ----------------
__global__ __launch_bounds__(512)
void gates_kernel(const float* __restrict__ comb,            // [256,1536] h_r|h_i|h_n
                  const unsigned short* __restrict__ Cpre,   // [16384, NPRE_] bf16
                  const float* __restrict__ bv,
                  float* __restrict__ hx,                    // [256,512] fp32
                  unsigned short* __restrict__ hxbf,         // [256,512] bf16
                  float* __restrict__ out, int t) {
    __shared__ float red[4][8];
    const int b = blockIdx.x, h = threadIdx.x;
    const int lane = h & 63, wv = h >> 6;
    const float* cb = comb + (size_t)b * NCAT_;
    const unsigned short* Cp = Cpre + (size_t)(b * T_ + t) * NPRE_;
    const float hxv = hx[(size_t)b * H_ + h];

    float d0 = hxv * bf2f(Cp[C_ZT1 + h]);   // -> s_r0 (key t1)
    float d1 = hxv * bf2f(Cp[C_ZIR + h]);   // -> s_r1 (key i_r)
    float d2 = hxv * bf2f(Cp[C_ZT2 + h]);   // -> s_i0
    float d3 = hxv * bf2f(Cp[C_ZII + h]);   // -> s_i1
    #pragma unroll
    for (int off = 32; off > 0; off >>= 1) {
        d0 += __shfl_down(d0, off);
        d1 += __shfl_down(d1, off);
        d2 += __shfl_down(d2, off);
        d3 += __shfl_down(d3, off);
    }
    if (lane == 0) { red[0][wv] = d0; red[1][wv] = d1; red[2][wv] = d2; red[3][wv] = d3; }
    __syncthreads();
    float s0 = 0.f, s1 = 0.f, s2 = 0.f, s3 = 0.f;
    #pragma unroll
    for (int ww = 0; ww < 8; ww++) {
        s0 += red[0][ww]; s1 += red[1][ww]; s2 += red[2][ww]; s3 += red[3][ww];
    }
    const float scale = 0.04419417382415922f; // 1/sqrt(512)
    const float sr0 = s0 + bf2f(Cp[C_CR0]);
    const float sr1 = s1 + bf2f(Cp[C_CR1]);
    const float si0 = s2 + bf2f(Cp[C_CI0]);
    const float si1 = s3 + bf2f(Cp[C_CI1]);
    const float p_r = 1.f / (1.f + expf((sr1 - sr0) * scale)); // weight of key0 (t1)
    const float p_i = 1.f / (1.f + expf((si1 - si0) * scale));

    const float bvh = bv[h];
    const float ctx_r = p_r * bf2f(Cp[C_VT1 + h]) + (1.f - p_r) * bf2f(Cp[C_VIR + h]) + bvh;
    const float ctx_i = p_i * bf2f(Cp[C_VT2 + h]) + (1.f - p_i) * bf2f(Cp[C_VII + h]) + bvh;

    const float rg = 1.f / (1.f + expf(-(ctx_r + cb[h])));
    const float ig = 1.f / (1.f + expf(-(ctx_i + cb[512 + h])));
    const float ng = tanhf(fmaf(rg, cb[1024 + h], bf2f(Cp[C_IN + h])));
    const float hy = ng + ig * (hxv - ng);
    out[(size_t)(b * T_ + t) * H_ + h] = hy;
    hx[(size_t)b * H_ + h] = hy;
    hxbf[(size_t)b * H_ + h] = f2bf(hy);
    if (t == T_ - 1)
        out[(size_t)B_ * T_ * H_ + (size_t)b * H_ + h] = hy;
}

extern "C" void kernel_launch(void* const* d_in, const int* in_sizes, int n_in,
                              void* d_out, int out_size, void* d_ws, size_t ws_size,
                              hipStream_t stream) {
    const float* input_feats = (const float*)d_in[0];
    const float* aux0   = (const float*)d_in[1];
    const float* W_ih   = (const float*)d_in[2];
    const float* b_ih   = (const float*)d_in[3];
    const float* W_fh0  = (const float*)d_in[4];
    const float* b_fh0  = (const float*)d_in[5];
    const float* W_hh   = (const float*)d_in[6];
    const float* b_hh   = (const float*)d_in[7];
    const float* Wq     = (const float*)d_in[8];
    const float* bq     = (const float*)d_in[9];
    const float* Wk     = (const float*)d_in[10];
    // d_in[11] = bk: cancels in the 2-way softmax.
    const float* Wv     = (const float*)d_in[12];
    const float* bv     = (const float*)d_in[13];
    float* out = (float*)d_out;

    char* ws = (char*)d_ws;
    size_t off = 0;
    auto alloc = [&](size_t bytes) -> void* {
        void* p = ws + off;
        off += (bytes + 255) & ~(size_t)255;
        return p;
    };
    unsigned short* Xbf   = (unsigned short*)alloc((size_t)BT_ * DIN_ * 2);
    unsigned short* Abf   = (unsigned short*)alloc((size_t)BT_ * DIN_ * 2);
    unsigned short* Wpre  = (unsigned short*)alloc((size_t)NPRE_ * DIN_ * 2);
    unsigned short* Cpre  = (unsigned short*)alloc((size_t)BT_ * NPRE_ * 2);
    unsigned short* WihT  = (unsigned short*)alloc((size_t)DIN_ * 1536 * 2);
    unsigned short* WfhT  = (unsigned short*)alloc((size_t)DIN_ * 1024 * 2);
    unsigned short* Acomp = (unsigned short*)alloc((size_t)1024 * 512 * 2); // [Wv_bf; Q]
    unsigned short* Wcat  = (unsigned short*)alloc((size_t)NCAT_ * H_ * 2);
    float* bpre = (float*)alloc((size_t)NPRE_ * 4);
    float* bqk  = (float*)alloc(512 * 4);
    float* tmpA = (float*)alloc(512 * 4);
    float* tmpB = (float*)alloc(512 * 4);
    float* tmpC = (float*)alloc(512 * 4);
    float* tmpD = (float*)alloc(512 * 4);
    float* comb = (float*)alloc((size_t)B_ * NCAT_ * 4);
    float* hx   = (float*)alloc((size_t)B_ * H_ * 4);
    unsigned short* hxbf = (unsigned short*)alloc((size_t)B_ * H_ * 2);

    hipMemsetAsync(hx, 0, (size_t)B_ * H_ * 4, stream);
    hipMemsetAsync(hxbf, 0, (size_t)B_ * H_ * 2, stream);

    auto cast = [&](const float* s, unsigned short* d, size_t n) {
        int n4 = (int)(n / 4);
        cast4_kernel<<<(n4 + 255) / 256, 256, 0, stream>>>(s, d, n4);
    };
    cast(input_feats, Xbf, (size_t)BT_ * DIN_);
    cast(aux0, Abf, (size_t)BT_ * DIN_);
    cast(W_ih + (size_t)1024 * DIN_, Wpre + (size_t)C_IN * DIN_, (size_t)512 * DIN_); // i_n rows
    cast(W_hh, Wcat, (size_t)NCAT_ * H_);
    cast(Wv, Acomp, (size_t)512 * 512);            // Acomp rows 0..511 = Wv

    tcast_kernel<<<dim3(DIN_ / 32, 1536 / 32), dim3(32, 8), 0, stream>>>(W_ih, WihT, 1536, DIN_);
    tcast_kernel<<<dim3(DIN_ / 32, 1024 / 32), dim3(32, 8), 0, stream>>>(W_fh0, WfhT, 1024, DIN_);

    // Q = Wq^T Wk  -> Acomp rows 512..1023
    wqk_kernel<<<dim3(32, 32), 256, 0, stream>>>(Wq, Wk, Acomp + (size_t)512 * 512);
    // bqk = Wk^T bq
    coldot_f32_kernel<<<2, 256, 0, stream>>>(Wk, 512, 512, bq, bqk, 512);

    // weight composes: C[m<512] = Wv o slice -> V rows; C[m>=512] = Q o slice -> z rows
    gemm_lds<<<dim3(16, 8), 256, 0, stream>>>(Acomp, Acomp, 1 << 30, WihT, 1536, nullptr,
        Wpre + (size_t)C_VIR * DIN_, Wpre + (size_t)C_ZIR * DIN_, 2, 512, DIN_, 512, DIN_);
    gemm_lds<<<dim3(16, 8), 256, 0, stream>>>(Acomp, Acomp, 1 << 30, WihT + 512, 1536, nullptr,
        Wpre + (size_t)C_VII * DIN_, Wpre + (size_t)C_ZII * DIN_, 2, 512, DIN_, 512, DIN_);
    gemm_lds<<<dim3(16, 8), 256, 0, stream>>>(Acomp, Acomp, 1 << 30, WfhT, 1024, nullptr,
        Wpre + (size_t)C_VT1 * DIN_, Wpre + (size_t)C_ZT1 * DIN_, 2, 512, DIN_, 512, DIN_);
    gemm_lds<<<dim3(16, 8), 256, 0, stream>>>(Acomp, Acomp, 1 << 30, WfhT + 512, 1024, nullptr,
        Wpre + (size_t)C_VT2 * DIN_, Wpre + (size_t)C_ZT2 * DIN_, 2, 512, DIN_, 512, DIN_);

    // scalar-column weight rows: w[d] = sum_j bqk[j]*Wsrc[j,d]
    coldot_bf16_kernel<<<8, 256, 0, stream>>>(W_ih, DIN_, 512, bqk, Wpre + (size_t)C_CR1 * DIN_, DIN_);
    coldot_bf16_kernel<<<8, 256, 0, stream>>>(W_ih + (size_t)512 * DIN_, DIN_, 512, bqk, Wpre + (size_t)C_CI1 * DIN_, DIN_);
    coldot_bf16_kernel<<<8, 256, 0, stream>>>(W_fh0, DIN_, 512, bqk, Wpre + (size_t)C_CR0 * DIN_, DIN_);
    coldot_bf16_kernel<<<8, 256, 0, stream>>>(W_fh0 + (size_t)512 * DIN_, DIN_, 512, bqk, Wpre + (size_t)C_CI0 * DIN_, DIN_);

    // biases
    hipMemcpyAsync(bpre + C_IN, b_ih + 1024, 512 * 4, hipMemcpyDeviceToDevice, stream);
    rowdot_kernel<<<2, 256, 0, stream>>>(Wv, 512, 512, b_ih, bpre + C_VIR, 512);
    rowdot_kernel<<<2, 256, 0, stream>>>(Wv, 512, 512, b_ih + 512, bpre + C_VII, 512);
    rowdot_kernel<<<2, 256, 0, stream>>>(Wv, 512, 512, b_fh0, bpre + C_VT1, 512);
    rowdot_kernel<<<2, 256, 0, stream>>>(Wv, 512, 512, b_fh0 + 512, bpre + C_VT2, 512);
    // z biases: (Wq^T (Wk b)) per source bias
    rowdot_kernel<<<2, 256, 0, stream>>>(Wk, 512, 512, b_ih, tmpA, 512);
    coldot_f32_kernel<<<2, 256, 0, stream>>>(Wq, 512, 512, tmpA, bpre + C_ZIR, 512);
    rowdot_kernel<<<2, 256, 0, stream>>>(Wk, 512, 512, b_ih + 512, tmpB, 512);
    coldot_f32_kernel<<<2, 256, 0, stream>>>(Wq, 512, 512, tmpB, bpre + C_ZII, 512);
    rowdot_kernel<<<2, 256, 0, stream>>>(Wk, 512, 512, b_fh0, tmpC, 512);
    coldot_f32_kernel<<<2, 256, 0, stream>>>(Wq, 512, 512, tmpC, bpre + C_ZT1, 512);
    rowdot_kernel<<<2, 256, 0, stream>>>(Wk, 512, 512, b_fh0 + 512, tmpD, 512);
    coldot_f32_kernel<<<2, 256, 0, stream>>>(Wq, 512, 512, tmpD, bpre + C_ZT2, 512);
    // scalar biases
    dot_kernel<<<1, 512, 0, stream>>>(bqk, b_ih, 512, bpre + C_CR1);
    dot_kernel<<<1, 512, 0, stream>>>(bqk, b_ih + 512, 512, bpre + C_CI1);
    dot_kernel<<<1, 512, 0, stream>>>(bqk, b_fh0, 512, bpre + C_CR0);
    dot_kernel<<<1, 512, 0, stream>>>(bqk, b_fh0 + 512, 512, bpre + C_CI0);

    // big precompute GEMM: Cpre[bt, :] bf16
    gemm_lds<<<dim3(NPRE_ / 128, BT_ / 128), 256, 0, stream>>>(
        Xbf, Abf, NSPLIT_, Wpre, DIN_, bpre, Cpre, nullptr, 1, 0, NPRE_, DIN_, NPRE_);

    // sequential recurrence: per step one small GEMM + gates
    for (int t = 0; t < T_; t++) {
        gemm_lds<<<dim3(NCAT_ / 128, B_ / 128), 256, 0, stream>>>(
            hxbf, hxbf, 1 << 30, Wcat, H_, b_hh, comb, nullptr, 0, 0, NCAT_, H_, NCAT_);
        gates_kernel<<<B_, 512, 0, stream>>>(comb, Cpre, bv, hx, hxbf, out, t);
    }
}